// Round 8
// baseline (307.138 us; speedup 1.0000x reference)
//
#include <hip/hip_runtime.h>
#include <hip/hip_bf16.h>

#define B_   2
#define S_   2048
#define D_   512
#define M_   64
#define T_   2112
#define BT_  4224
#define H_   8
#define WIN_ 512

typedef short s16x8 __attribute__((ext_vector_type(8)));
typedef float f32x4 __attribute__((ext_vector_type(4)));
typedef unsigned short ushort_t;

__device__ __forceinline__ float siluf(float x) {
    float s = 1.0f / (1.0f + expf(-x));
    return x * s;
}
__device__ __forceinline__ float dsiluf(float x) {
    float s = 1.0f / (1.0f + expf(-x));
    return s * (1.0f + x * (1.0f - s));
}
__device__ __forceinline__ float bf2f(ushort_t u) {
    union { float f; unsigned int i; } x; x.i = ((unsigned int)u) << 16; return x.f;
}
__device__ __forceinline__ ushort_t f2bf(float f) {
    union { float f; unsigned int i; } x; x.f = f;
    unsigned int r = x.i + 0x7FFFu + ((x.i >> 16) & 1u);
    return (ushort_t)(r >> 16);
}
__device__ __forceinline__ void pack8(ushort_t* dst, const float* v) {
    ushort_t tmp[8];
#pragma unroll
    for (int i = 0; i < 8; ++i) tmp[i] = f2bf(v[i]);
    *(int4*)dst = *(const int4*)tmp;
}

// ---------------- fused prep: weight cvt (9), l1 transpose, xm build, alr ----------------
struct PrepArgs {
    const float* wsrc[9]; ushort_t* wdst[9];
    const float* l1src;   ushort_t* l1t;
    const float* x; const float* meta; ushort_t* xm;
    const float* wlr; float* alr;
};
__global__ __launch_bounds__(256)
void prep_kernel(PrepArgs p) {
    __shared__ float tbuf[32][33];
    int bid = blockIdx.x;
    int tid = threadIdx.x;
    if (bid < 1152) {
        int w = bid >> 7;
        int idx = ((bid & 127) << 8) + tid;
        const float* src = p.wsrc[w] + (size_t)idx * 8;
        float v[8];
        *(float4*)&v[0] = *(const float4*)src;
        *(float4*)&v[4] = *(const float4*)(src + 4);
        pack8(p.wdst[w] + (size_t)idx * 8, v);
    } else if (bid < 1408) {
        int wz = bid - 1152;
        int bx = wz & 15, by = wz >> 4;
        int tr = tid >> 3, tc = (tid & 7) * 4;
        int r0 = by * 32, c0 = bx * 32;
        *(float4*)&tbuf[tr][tc] = *(const float4*)&p.l1src[(size_t)(r0 + tr) * 512 + c0 + tc];
        __syncthreads();
        ushort_t o[4];
#pragma unroll
        for (int i = 0; i < 4; ++i) o[i] = f2bf(tbuf[tc + i][tr]);
        *(ushort2*)&p.l1t[(size_t)(c0 + tr) * 512 + r0 + tc] = *(ushort2*)&o[0];
        *(ushort2*)&p.l1t[(size_t)(c0 + tr) * 512 + r0 + tc + 2] = *(ushort2*)&o[2];
    } else if (bid < 2464) {
        int idx = (bid - 1408) * 256 + tid;
        int seg = idx & 63;
        int row = idx >> 6;
        int b = row / T_;
        int t = row - b * T_;
        const float* src;
        if (t < M_) src = p.meta + (size_t)t * 512 + seg * 8;
        else        src = p.x + ((size_t)b * S_ + (t - M_)) * 512 + seg * 8;
        float v[8];
        *(float4*)&v[0] = *(const float4*)src;
        *(float4*)&v[4] = *(const float4*)(src + 4);
        pack8(p.xm + (size_t)row * 512 + seg * 8, v);
    } else {
        int r = (bid - 2464) * 4 + (tid >> 6);
        int lane = tid & 63;
        int b = r / T_;
        int t = r - b * T_;
        const float* row = (t < M_) ? (p.meta + (size_t)t * 512)
                                    : (p.x + ((size_t)b * S_ + (t - M_)) * 512);
        float s = 0.f;
#pragma unroll
        for (int k = 0; k < 8; ++k) s = fmaf(row[lane + k * 64], p.wlr[lane + k * 64], s);
#pragma unroll
        for (int off = 32; off >= 1; off >>= 1) s += __shfl_xor(s, off, 64);
        if (lane == 0) p.alr[r] = 0.01f / (1.0f + expf(-s));
    }
}

// ---------------- 128x128-tile bf16 MFMA GEMM for N=1536 fused projections ----------------
// __launch_bounds__(256,2): 2 waves/SIMD -> <=256 VGPR budget, NO SPILL (round-7 regression fix)
// MODE 0 QKV: sg=by>>2 -> 0:qq->U0, 1:kk->U1 + kkT->U2, 2:vv->U3
// MODE 5 SWAQKV: 0:qh->U0, 1:kh->U1, 2:vhT(per-batch transposed)->U2
template<int MODE>
__global__ __launch_bounds__(256, 2)
void mgemm128(const ushort_t* __restrict__ A, const ushort_t* __restrict__ Bt,
              ushort_t* __restrict__ U0, ushort_t* __restrict__ U1,
              ushort_t* __restrict__ U2, ushort_t* __restrict__ U3) {
    __shared__ ushort_t As[128 * 64];
    __shared__ ushort_t Bs[128 * 64];
    int tid = threadIdx.x;
    int m0 = blockIdx.x * 128;
    int by = blockIdx.y;
    int n0 = by * 128;
    int wave = tid >> 6, lane = tid & 63;
    int fr = lane & 15, fq = lane >> 4;
    int wm = (wave & 1) << 6;          // 0/64
    int wn = (wave >> 1) << 6;         // 0/64
    int srow = tid >> 1;               // 0..127
    int sseg = (tid & 1) << 2;         // 0 or 4
    int ssw = srow & 7;
    const ushort_t* ga = A  + (size_t)(m0 + srow) * 512 + sseg * 8;
    const ushort_t* gb = Bt + (size_t)(n0 + srow) * 512 + sseg * 8;
    int4 av[4], bv[4];
#pragma unroll
    for (int p = 0; p < 4; ++p) {
        av[p] = *(const int4*)(ga + p * 8);
        bv[p] = *(const int4*)(gb + p * 8);
    }
    f32x4 acc[4][4] = {};
    for (int k0 = 0; k0 < 512; k0 += 64) {
        __syncthreads();
#pragma unroll
        for (int p = 0; p < 4; ++p) {
            *(int4*)&As[srow * 64 + ((sseg + p) ^ ssw) * 8] = av[p];
            *(int4*)&Bs[srow * 64 + ((sseg + p) ^ ssw) * 8] = bv[p];
        }
        __syncthreads();
        if (k0 + 64 < 512) {
#pragma unroll
            for (int p = 0; p < 4; ++p) {
                av[p] = *(const int4*)(ga + k0 + 64 + p * 8);
                bv[p] = *(const int4*)(gb + k0 + 64 + p * 8);
            }
        }
#pragma unroll
        for (int ks = 0; ks < 2; ++ks) {
            int seg = fq + ks * 4;
            int sx = (seg ^ (fr & 7)) * 8;
            s16x8 af[4], bf[4];
#pragma unroll
            for (int i = 0; i < 4; ++i) {
                af[i] = *(const s16x8*)&As[(wm + i * 16 + fr) * 64 + sx];
                bf[i] = *(const s16x8*)&Bs[(wn + i * 16 + fr) * 64 + sx];
            }
#pragma unroll
            for (int i = 0; i < 4; ++i)
#pragma unroll
                for (int j = 0; j < 4; ++j)
                    acc[i][j] = __builtin_amdgcn_mfma_f32_16x16x32_bf16(af[i], bf[j], acc[i][j], 0, 0, 0);
        }
    }
    int sg = by >> 2;
#pragma unroll
    for (int i = 0; i < 4; ++i) {
        int row0 = m0 + wm + i * 16 + fq * 4;
#pragma unroll
        for (int j = 0; j < 4; ++j) {
            int cl = (by & 3) * 128 + wn + j * 16 + fr;
            ushort_t t4[4];
#pragma unroll
            for (int r = 0; r < 4; ++r) t4[r] = f2bf(acc[i][j][r]);
            if (MODE == 0) {
                if (sg == 0) {
#pragma unroll
                    for (int r = 0; r < 4; ++r) U0[(size_t)(row0 + r) * 512 + cl] = t4[r];
                } else if (sg == 1) {
#pragma unroll
                    for (int r = 0; r < 4; ++r) U1[(size_t)(row0 + r) * 512 + cl] = t4[r];
                    *(uint2*)&U2[(size_t)cl * BT_ + row0] = *(uint2*)t4;
                } else {
#pragma unroll
                    for (int r = 0; r < 4; ++r) U3[(size_t)(row0 + r) * 512 + cl] = t4[r];
                }
            } else {
                if (sg == 0) {
#pragma unroll
                    for (int r = 0; r < 4; ++r) U0[(size_t)(row0 + r) * 512 + cl] = t4[r];
                } else if (sg == 1) {
#pragma unroll
                    for (int r = 0; r < 4; ++r) U1[(size_t)(row0 + r) * 512 + cl] = t4[r];
                } else {
                    int bb = row0 / T_;
                    int t0 = row0 - bb * T_;
                    *(uint2*)&U2[((size_t)(bb * 512) + cl) * T_ + t0] = *(uint2*)t4;
                }
            }
        }
    }
}

// ---------------- 128x128-tile dW NT GEMM (both layers), split-K 11x384 ----------------
__global__ __launch_bounds__(256, 2)
void gemm_dw128(const ushort_t* __restrict__ A1T, const ushort_t* __restrict__ B1T,
                const ushort_t* __restrict__ A0T, const ushort_t* __restrict__ B0T,
                float* __restrict__ Cpart) {
    __shared__ ushort_t As[128 * 64];
    __shared__ ushort_t Bs[128 * 64];
    int tid = threadIdx.x;
    int zz = blockIdx.z;
    int layer = (zz >= 11);
    int slice = layer ? (zz - 11) : zz;
    const ushort_t* AT  = layer ? A1T : A0T;
    const ushort_t* BT2 = layer ? B1T : B0T;
    int m0 = blockIdx.x * 128, n0 = blockIdx.y * 128;
    int kbase = slice * 384;
    int wave = tid >> 6, lane = tid & 63;
    int fr = lane & 15, fq = lane >> 4;
    int wm = (wave & 1) << 6;
    int wn = (wave >> 1) << 6;
    int srow = tid >> 1;
    int sseg = (tid & 1) << 2;
    int ssw = srow & 7;
    const ushort_t* ga = AT  + (size_t)(m0 + srow) * BT_ + kbase + sseg * 8;
    const ushort_t* gb = BT2 + (size_t)(n0 + srow) * BT_ + kbase + sseg * 8;
    int4 av[4], bv[4];
#pragma unroll
    for (int p = 0; p < 4; ++p) {
        av[p] = *(const int4*)(ga + p * 8);
        bv[p] = *(const int4*)(gb + p * 8);
    }
    f32x4 acc[4][4] = {};
    for (int kt = 0; kt < 6; ++kt) {
        __syncthreads();
#pragma unroll
        for (int p = 0; p < 4; ++p) {
            *(int4*)&As[srow * 64 + ((sseg + p) ^ ssw) * 8] = av[p];
            *(int4*)&Bs[srow * 64 + ((sseg + p) ^ ssw) * 8] = bv[p];
        }
        __syncthreads();
        if (kt < 5) {
            int koff = (kt + 1) * 64;
#pragma unroll
            for (int p = 0; p < 4; ++p) {
                av[p] = *(const int4*)(ga + koff + p * 8);
                bv[p] = *(const int4*)(gb + koff + p * 8);
            }
        }
#pragma unroll
        for (int ks = 0; ks < 2; ++ks) {
            int seg = fq + ks * 4;
            int sx = (seg ^ (fr & 7)) * 8;
            s16x8 af[4], bf[4];
#pragma unroll
            for (int i = 0; i < 4; ++i) {
                af[i] = *(const s16x8*)&As[(wm + i * 16 + fr) * 64 + sx];
                bf[i] = *(const s16x8*)&Bs[(wn + i * 16 + fr) * 64 + sx];
            }
#pragma unroll
            for (int i = 0; i < 4; ++i)
#pragma unroll
                for (int j = 0; j < 4; ++j)
                    acc[i][j] = __builtin_amdgcn_mfma_f32_16x16x32_bf16(af[i], bf[j], acc[i][j], 0, 0, 0);
        }
    }
    float* C = Cpart + (size_t)zz * 262144;
#pragma unroll
    for (int i = 0; i < 4; ++i)
#pragma unroll
        for (int j = 0; j < 4; ++j)
#pragma unroll
            for (int r = 0; r < 4; ++r)
                C[(size_t)(m0 + wm + i * 16 + fq * 4 + r) * 512 + n0 + wn + j * 16 + fr] =
                    acc[i][j][r];
}

// ---------------- 64x64-tile bf16 MFMA GEMM (N=512 chain) with fused epilogues ----------------
// MODE 1 H1  (h1 bf->U0 + h1T->U2, dsilu(z0) bf->U3; residual kk=U1)
// MODE 2 Z1DP(dz1->U0 + dz1T->U2, dp bf->U4; reads h1b=U1, v=U3, alr)
// MODE 3 DH1DZ0 (dz0 T-major->U0; reads dp=U1, dsz0=U2)
// MODE 4 RES2 (U0 = bf(U1)+silu(acc))
// MODE 6 WO (row-filtered fp32 out->F0)
template<int MODE>
__global__ __launch_bounds__(256)
void mgemm(const ushort_t* __restrict__ A, const ushort_t* __restrict__ Bt,
           float* __restrict__ F0,
           ushort_t* __restrict__ U0, ushort_t* __restrict__ U1,
           ushort_t* __restrict__ U2, ushort_t* __restrict__ U3,
           ushort_t* __restrict__ U4,
           const float* __restrict__ alrp) {
    __shared__ ushort_t As[64 * 64];
    __shared__ ushort_t Bs[64 * 64];
    int tid = threadIdx.x;
    int m0 = blockIdx.x * 64, n0 = blockIdx.y * 64;
    int srow = tid >> 2;
    int sseg = (tid & 3) << 1;
    int wid = tid >> 6;
    int lane = tid & 63;
    int wm = (wid & 1) << 5;
    int wn = (wid >> 1) << 5;
    int fr = lane & 15;
    int fq = lane >> 4;
    int sw = srow & 7;
    const ushort_t* ga = A  + (size_t)(m0 + srow) * 512 + sseg * 8;
    const ushort_t* gb = Bt + (size_t)(n0 + srow) * 512 + sseg * 8;
    int4 av0 = *(const int4*)ga;
    int4 av1 = *(const int4*)(ga + 8);
    int4 bv0 = *(const int4*)gb;
    int4 bv1 = *(const int4*)(gb + 8);
    f32x4 acc[2][2] = {};
    for (int k0 = 0; k0 < 512; k0 += 64) {
        __syncthreads();
        *(int4*)&As[srow * 64 + ((sseg    ) ^ sw) * 8] = av0;
        *(int4*)&As[srow * 64 + ((sseg + 1) ^ sw) * 8] = av1;
        *(int4*)&Bs[srow * 64 + ((sseg    ) ^ sw) * 8] = bv0;
        *(int4*)&Bs[srow * 64 + ((sseg + 1) ^ sw) * 8] = bv1;
        __syncthreads();
        if (k0 + 64 < 512) {
            av0 = *(const int4*)(ga + k0 + 64);
            av1 = *(const int4*)(ga + k0 + 72);
            bv0 = *(const int4*)(gb + k0 + 64);
            bv1 = *(const int4*)(gb + k0 + 72);
        }
#pragma unroll
        for (int ks = 0; ks < 2; ++ks) {
            int seg = fq + ks * 4;
            int rA0 = wm + fr,      rA1 = wm + 16 + fr;
            int rB0 = wn + fr,      rB1 = wn + 16 + fr;
            s16x8 a0 = *(const s16x8*)&As[rA0 * 64 + (seg ^ (rA0 & 7)) * 8];
            s16x8 a1 = *(const s16x8*)&As[rA1 * 64 + (seg ^ (rA1 & 7)) * 8];
            s16x8 b0 = *(const s16x8*)&Bs[rB0 * 64 + (seg ^ (rB0 & 7)) * 8];
            s16x8 b1 = *(const s16x8*)&Bs[rB1 * 64 + (seg ^ (rB1 & 7)) * 8];
            acc[0][0] = __builtin_amdgcn_mfma_f32_16x16x32_bf16(a0, b0, acc[0][0], 0, 0, 0);
            acc[0][1] = __builtin_amdgcn_mfma_f32_16x16x32_bf16(a0, b1, acc[0][1], 0, 0, 0);
            acc[1][0] = __builtin_amdgcn_mfma_f32_16x16x32_bf16(a1, b0, acc[1][0], 0, 0, 0);
            acc[1][1] = __builtin_amdgcn_mfma_f32_16x16x32_bf16(a1, b1, acc[1][1], 0, 0, 0);
        }
    }
#pragma unroll
    for (int i = 0; i < 2; ++i) {
        int row0 = m0 + wm + i * 16 + fq * 4;
        float c4[4];
        if (MODE == 2) {
#pragma unroll
            for (int r = 0; r < 4; ++r) c4[r] = (2.0f / 512.0f) * alrp[row0 + r];
        }
#pragma unroll
        for (int j = 0; j < 2; ++j) {
            int col = n0 + wn + j * 16 + fr;
            if (MODE == 1) {
                ushort_t t4[4];
#pragma unroll
                for (int r = 0; r < 4; ++r) {
                    size_t off = (size_t)(row0 + r) * 512 + col;
                    float z = acc[i][j][r];
                    float h = bf2f(U1[off]) + siluf(z);
                    ushort_t hb = f2bf(h);
                    U0[off] = hb;
                    t4[r] = hb;
                    U3[off] = f2bf(dsiluf(z));
                }
                *(uint2*)&U2[(size_t)col * BT_ + row0] = *(uint2*)t4;
            } else if (MODE == 2) {
                ushort_t t4[4];
#pragma unroll
                for (int r = 0; r < 4; ++r) {
                    size_t off = (size_t)(row0 + r) * 512 + col;
                    float z = acc[i][j][r];
                    float s = 1.f / (1.f + expf(-z));
                    float d = c4[r] * (bf2f(U1[off]) + z * s - bf2f(U3[off]));
                    U4[off] = f2bf(d);
                    ushort_t u = f2bf(d * (s * (1.f + z * (1.f - s))));
                    U0[off] = u;
                    t4[r] = u;
                }
                *(uint2*)&U2[(size_t)col * BT_ + row0] = *(uint2*)t4;
            } else if (MODE == 3) {
                ushort_t t4[4];
#pragma unroll
                for (int r = 0; r < 4; ++r) {
                    size_t off = (size_t)(row0 + r) * 512 + col;
                    float g = bf2f(U1[off]) + acc[i][j][r];
                    t4[r] = f2bf(g * bf2f(U2[off]));
                }
                *(uint2*)&U0[(size_t)col * BT_ + row0] = *(uint2*)t4;
            } else if (MODE == 4) {
#pragma unroll
                for (int r = 0; r < 4; ++r) {
                    size_t off = (size_t)(row0 + r) * 512 + col;
                    U0[off] = f2bf(bf2f(U1[off]) + siluf(acc[i][j][r]));
                }
            } else if (MODE == 6) {
#pragma unroll
                for (int r = 0; r < 4; ++r) {
                    int row = row0 + r;
                    int bb = row / T_;
                    int t = row - bb * T_;
                    if (t >= M_) F0[((size_t)bb * S_ + (t - M_)) * 512 + col] = acc[i][j][r];
                }
            }
        }
    }
}

// ---------------- AdamW first step (11 partial slices per layer) -> bf16 weights ----------------
__global__ void adam_kernel(const float* __restrict__ W, const float* __restrict__ dWp,
                            ushort_t* __restrict__ Wnb) {
    int idx = blockIdx.x * 256 + threadIdx.x;
    int layer = idx >> 18;
    int i = idx & 262143;
    const float* base = dWp + (size_t)layer * 11 * 262144 + i;
    float g = 0.f;
#pragma unroll
    for (int z = 0; z < 11; ++z) g += base[(size_t)z * 262144];
    g *= (1.0f / 16.0f);
    float w = W[idx];
    float o = w * (1.0f - 1e-5f) - 1e-3f * g / (fabsf(g) + 1e-8f);
    Wnb[idx] = f2bf(o);
}

// ---------------- MFMA flash SWA, unnormalized softmax (scores bounded) ----------------
__global__ __launch_bounds__(256)
void swa_mfma(const ushort_t* __restrict__ qh, const ushort_t* __restrict__ kh,
              const ushort_t* __restrict__ vhT, ushort_t* __restrict__ ao) {
    __shared__ ushort_t Qs[64 * 64];
    __shared__ ushort_t Ks[64 * 64];
    __shared__ ushort_t Vs[64 * 64];
    __shared__ ushort_t Pw[4][16 * 72];
    int qt = 32 - (int)blockIdx.x;
    int hh = blockIdx.y;
    int b  = blockIdx.z;
    int tid = threadIdx.x;
    int wave = tid >> 6, lane = tid & 63;
    int fr = lane & 15, fq = lane >> 4;
    int tok = tid & 63, cs0 = tid >> 6;

    {
        const ushort_t* src = qh + ((size_t)(b * T_ + qt * 64 + tok)) * 512 + hh * 64;
#pragma unroll
        for (int p = 0; p < 2; ++p) {
            int seg = cs0 + p * 4;
            *(int4*)&Qs[tok * 64 + ((seg ^ (tok & 7)) << 3)] = *(const int4*)(src + seg * 8);
        }
    }
    __syncthreads();
    s16x8 qf0 = *(const s16x8*)&Qs[(wave * 16 + fr) * 64 + (((0 + fq) ^ (fr & 7)) << 3)];
    s16x8 qf1 = *(const s16x8*)&Qs[(wave * 16 + fr) * 64 + (((4 + fq) ^ (fr & 7)) << 3)];

    int i_q = qt * 64 + wave * 16 + fr;
    int iqmin = qt * 64 + wave * 16;
    float l_i = 0.f;
    f32x4 o[4] = {};
    int jstart = qt * 64 - (WIN_ - 1);
    if (jstart < 0) jstart = 0;
    jstart &= ~63;
    int jend = qt * 64;
    const ushort_t* kp = kh + ((size_t)(b * T_ + jstart + tok)) * 512 + hh * 64;
    const ushort_t* vp = vhT + ((size_t)(b * 512 + hh * 64 + tok)) * T_ + jstart;
    int4 ka = *(const int4*)(kp + cs0 * 8);
    int4 kb2 = *(const int4*)(kp + (cs0 + 4) * 8);
    int4 va = *(const int4*)(vp + cs0 * 8);
    int4 vb2 = *(const int4*)(vp + (cs0 + 4) * 8);
    for (int jb = jstart; jb <= jend; jb += 64) {
        __syncthreads();
        *(int4*)&Ks[tok * 64 + (((cs0    ) ^ (tok & 7)) << 3)] = ka;
        *(int4*)&Ks[tok * 64 + (((cs0 + 4) ^ (tok & 7)) << 3)] = kb2;
        *(int4*)&Vs[tok * 64 + (((cs0    ) ^ (tok & 7)) << 3)] = va;
        *(int4*)&Vs[tok * 64 + (((cs0 + 4) ^ (tok & 7)) << 3)] = vb2;
        __syncthreads();
        if (jb + 64 <= jend) {
            kp += 64 * 512;
            vp += 64;
            ka  = *(const int4*)(kp + cs0 * 8);
            kb2 = *(const int4*)(kp + (cs0 + 4) * 8);
            va  = *(const int4*)(vp + cs0 * 8);
            vb2 = *(const int4*)(vp + (cs0 + 4) * 8);
        }
        f32x4 sa[4] = {};
#pragma unroll
        for (int kf = 0; kf < 4; ++kf) {
            int krow = kf * 16 + fr;
            s16x8 a0 = *(const s16x8*)&Ks[krow * 64 + (((0 + fq) ^ (fr & 7)) << 3)];
            s16x8 a1 = *(const s16x8*)&Ks[krow * 64 + (((4 + fq) ^ (fr & 7)) << 3)];
            sa[kf] = __builtin_amdgcn_mfma_f32_16x16x32_bf16(a0, qf0, sa[kf], 0, 0, 0);
            sa[kf] = __builtin_amdgcn_mfma_f32_16x16x32_bf16(a1, qf1, sa[kf], 0, 0, 0);
        }
        float psum = 0.f;
        bool full = (jb + 63 <= iqmin) && (jb >= iqmin + 15 - (WIN_ - 1));
        if (full) {
#pragma unroll
            for (int kf = 0; kf < 4; ++kf)
#pragma unroll
                for (int r = 0; r < 4; ++r) {
                    float p = __expf(sa[kf][r] * 0.125f);
                    ushort_t pb = f2bf(p);
                    psum += bf2f(pb);
                    Pw[wave][fr * 72 + kf * 16 + fq * 4 + r] = pb;
                }
        } else {
#pragma unroll
            for (int kf = 0; kf < 4; ++kf)
#pragma unroll
                for (int r = 0; r < 4; ++r) {
                    int j2 = jb + kf * 16 + fq * 4 + r;
                    bool valid = (j2 <= i_q) && (i_q - j2 < WIN_);
                    float p = valid ? __expf(sa[kf][r] * 0.125f) : 0.f;
                    ushort_t pb = f2bf(p);
                    psum += bf2f(pb);
                    Pw[wave][fr * 72 + kf * 16 + fq * 4 + r] = pb;
                }
        }
        psum += __shfl_xor(psum, 16);
        psum += __shfl_xor(psum, 32);
        l_i += psum;
#pragma unroll
        for (int ks = 0; ks < 2; ++ks) {
            s16x8 pa = *(const s16x8*)&Pw[wave][fr * 72 + ks * 32 + fq * 8];
#pragma unroll
            for (int nf = 0; nf < 4; ++nf) {
                int vrow = nf * 16 + fr;
                s16x8 bv = *(const s16x8*)&Vs[vrow * 64 + (((ks * 4 + fq) ^ (fr & 7)) << 3)];
                o[nf] = __builtin_amdgcn_mfma_f32_16x16x32_bf16(pa, bv, o[nf], 0, 0, 0);
            }
        }
    }
    float linv = 1.0f / l_i;
    float l0 = __shfl(linv, fq * 4 + 0);
    float l1 = __shfl(linv, fq * 4 + 1);
    float l2 = __shfl(linv, fq * 4 + 2);
    float l3 = __shfl(linv, fq * 4 + 3);
#pragma unroll
    for (int nf = 0; nf < 4; ++nf) {
        int col = hh * 64 + nf * 16 + fr;
        size_t row0 = (size_t)(b * T_) + qt * 64 + wave * 16 + fq * 4;
        ao[(row0 + 0) * 512 + col] = f2bf(o[nf][0] * l0);
        ao[(row0 + 1) * 512 + col] = f2bf(o[nf][1] * l1);
        ao[(row0 + 2) * 512 + col] = f2bf(o[nf][2] * l2);
        ao[(row0 + 3) * 512 + col] = f2bf(o[nf][3] * l3);
    }
}

extern "C" void kernel_launch(void* const* d_in, const int* in_sizes, int n_in,
                              void* d_out, int out_size, void* d_ws, size_t ws_size,
                              hipStream_t stream) {
    (void)in_sizes; (void)n_in; (void)out_size; (void)ws_size;
    const float* x      = (const float*)d_in[0];
    const float* meta   = (const float*)d_in[1];
    const float* lmm_w  = (const float*)d_in[2];
    const float* w_q    = (const float*)d_in[3];
    const float* w_k    = (const float*)d_in[4];
    const float* w_v    = (const float*)d_in[5];
    const float* w_lr   = (const float*)d_in[6];
    const float* swa_wq = (const float*)d_in[7];
    const float* swa_wk = (const float*)d_in[8];
    const float* swa_wv = (const float*)d_in[9];
    const float* swa_wo = (const float*)d_in[10];
    float* out = (float*)d_out;
    float* ws  = (float*)d_ws;

    const size_t BTD = (size_t)BT_ * D_;       // 2162688
    float* alr = ws;                           // BT_
    float* dWp = alr + BT_;                    // [2][11][262144] fp32
    ushort_t* xb = (ushort_t*)(dWp + 22 * 262144);
    ushort_t* B0  = xb + 0 * BTD;   // xm / dz0T / h1q
    ushort_t* B1  = xb + 1 * BTD;   // qq / qh
    ushort_t* B2  = xb + 2 * BTD;   // kk / ao
    ushort_t* B3  = xb + 3 * BTD;   // kkT
    ushort_t* B4  = xb + 4 * BTD;   // vv / r
    ushort_t* B5  = xb + 5 * BTD;   // h1b / kh
    ushort_t* B6  = xb + 6 * BTD;   // h1T / vhT
    ushort_t* B7  = xb + 7 * BTD;   // dz1
    ushort_t* B8  = xb + 8 * BTD;   // dz1T
    ushort_t* B9  = xb + 9 * BTD;   // dp bf
    ushort_t* B10 = xb + 10 * BTD;  // dsilu(z0) bf
    ushort_t* wbf = xb + 11 * BTD;
    ushort_t* wq_bf  = wbf + 0 * 262144;       // wq,wk,wv contiguous
    ushort_t* l0_bf  = wbf + 3 * 262144;
    ushort_t* l1_bf  = wbf + 4 * 262144;
    ushort_t* sq_bf  = wbf + 5 * 262144;       // sq,sk,sv contiguous
    ushort_t* wo_bf  = wbf + 8 * 262144;
    ushort_t* l1t_bf = wbf + 9 * 262144;
    ushort_t* wn_bf  = wbf + 10 * 262144;      // 2 layers

    dim3 blk(256);
    dim3 gg(66, 8);
    dim3 g128(33, 12);
    dim3 gdw(4, 4, 22);

    PrepArgs pa;
    pa.wsrc[0] = w_q;    pa.wdst[0] = wq_bf;
    pa.wsrc[1] = w_k;    pa.wdst[1] = wbf + 1 * 262144;
    pa.wsrc[2] = w_v;    pa.wdst[2] = wbf + 2 * 262144;
    pa.wsrc[3] = lmm_w;  pa.wdst[3] = l0_bf;
    pa.wsrc[4] = lmm_w + 262144; pa.wdst[4] = l1_bf;
    pa.wsrc[5] = swa_wq; pa.wdst[5] = sq_bf;
    pa.wsrc[6] = swa_wk; pa.wdst[6] = wbf + 6 * 262144;
    pa.wsrc[7] = swa_wv; pa.wdst[7] = wbf + 7 * 262144;
    pa.wsrc[8] = swa_wo; pa.wdst[8] = wo_bf;
    pa.l1src = lmm_w + 262144; pa.l1t = l1t_bf;
    pa.x = x; pa.meta = meta; pa.xm = B0;
    pa.wlr = w_lr; pa.alr = alr;

    prep_kernel<<<dim3(3520), blk, 0, stream>>>(pa);
    // qq(B1)/kk(B2)+kkT(B3)/vv(B4) = xm @ {wq,wk,wv}^T   (128-tile)
    mgemm128<0><<<g128, blk, 0, stream>>>(B0, wq_bf, B1, B2, B3, B4);
    // h1b(B5)+h1T(B6), dsz0(B10); residual kk(B2)
    mgemm<1><<<gg, blk, 0, stream>>>(B2, l0_bf, nullptr, B5, B2, B6, B10, nullptr, nullptr);
    // dz1(B7)+dz1T(B8), dp(B9); reads h1b(B5), v(B4), alr
    mgemm<2><<<gg, blk, 0, stream>>>(B5, l1_bf, nullptr, B7, B5, B8, B4, B9, alr);
    // dz0T(B0); reads dp(B9), dsz0(B10)
    mgemm<3><<<gg, blk, 0, stream>>>(B7, l1t_bf, nullptr, B0, B9, B10, nullptr, nullptr, nullptr);
    // dW0 = dz0T x kkT (zz 0..10), dW1 = dz1T x h1T (zz 11..21)   (128-tile)
    gemm_dw128<<<gdw, blk, 0, stream>>>(B8, B6, B0, B3, dWp);
    adam_kernel<<<dim3(2048), blk, 0, stream>>>(lmm_w, dWp, wn_bf);
    // h1q(B0) = qq + silu(qq@Wn0^T)
    mgemm<4><<<gg, blk, 0, stream>>>(B1, wn_bf, nullptr, B0, B1, nullptr, nullptr, nullptr, nullptr);
    // r(B4) = h1q + silu(h1q@Wn1^T)
    mgemm<4><<<gg, blk, 0, stream>>>(B0, wn_bf + 262144, nullptr, B4, B0, nullptr, nullptr, nullptr, nullptr);
    // qh(B1)/kh(B5)/vhT(B6) = r @ {sq,sk,sv}^T   (128-tile)
    mgemm128<5><<<g128, blk, 0, stream>>>(B4, sq_bf, B1, B5, B6, nullptr);
    swa_mfma<<<dim3(33, 8, 2), blk, 0, stream>>>(B1, B5, B6, B2); // ao(B2)
    // out = ao @ wo^T (row-filtered fp32)
    mgemm<6><<<gg, blk, 0, stream>>>(B2, wo_bf, out, nullptr, nullptr, nullptr, nullptr, nullptr, nullptr);
}

// Round 9
// 210.515 us; speedup vs baseline: 1.4590x; 1.4590x over previous
//
#include <hip/hip_runtime.h>
#include <hip/hip_bf16.h>

#define B_   2
#define S_   2048
#define D_   512
#define M_   64
#define T_   2112
#define BT_  4224
#define H_   8
#define WIN_ 512

typedef short s16x8 __attribute__((ext_vector_type(8)));
typedef float f32x4 __attribute__((ext_vector_type(4)));
typedef unsigned short ushort_t;

__device__ __forceinline__ float siluf(float x) {
    float s = 1.0f / (1.0f + expf(-x));
    return x * s;
}
__device__ __forceinline__ float dsiluf(float x) {
    float s = 1.0f / (1.0f + expf(-x));
    return s * (1.0f + x * (1.0f - s));
}
__device__ __forceinline__ float bf2f(ushort_t u) {
    union { float f; unsigned int i; } x; x.i = ((unsigned int)u) << 16; return x.f;
}
__device__ __forceinline__ ushort_t f2bf(float f) {
    union { float f; unsigned int i; } x; x.f = f;
    unsigned int r = x.i + 0x7FFFu + ((x.i >> 16) & 1u);
    return (ushort_t)(r >> 16);
}
__device__ __forceinline__ void pack8(ushort_t* dst, const float* v) {
    ushort_t tmp[8];
#pragma unroll
    for (int i = 0; i < 8; ++i) tmp[i] = f2bf(v[i]);
    *(int4*)dst = *(const int4*)tmp;
}

// ---------------- fused prep: weight cvt (9), l1 transpose, xm build, alr ----------------
struct PrepArgs {
    const float* wsrc[9]; ushort_t* wdst[9];
    const float* l1src;   ushort_t* l1t;
    const float* x; const float* meta; ushort_t* xm;
    const float* wlr; float* alr;
};
__global__ __launch_bounds__(256)
void prep_kernel(PrepArgs p) {
    __shared__ float tbuf[32][33];
    int bid = blockIdx.x;
    int tid = threadIdx.x;
    if (bid < 1152) {                       // weight cvt: 9 x 128 blocks
        int w = bid >> 7;
        int idx = ((bid & 127) << 8) + tid;
        const float* src = p.wsrc[w] + (size_t)idx * 8;
        float v[8];
        *(float4*)&v[0] = *(const float4*)src;
        *(float4*)&v[4] = *(const float4*)(src + 4);
        pack8(p.wdst[w] + (size_t)idx * 8, v);
    } else if (bid < 1408) {                // l1 transpose: 256 blocks
        int wz = bid - 1152;
        int bx = wz & 15, by = wz >> 4;
        int tr = tid >> 3, tc = (tid & 7) * 4;
        int r0 = by * 32, c0 = bx * 32;
        *(float4*)&tbuf[tr][tc] = *(const float4*)&p.l1src[(size_t)(r0 + tr) * 512 + c0 + tc];
        __syncthreads();
        ushort_t o[4];
#pragma unroll
        for (int i = 0; i < 4; ++i) o[i] = f2bf(tbuf[tc + i][tr]);
        *(ushort2*)&p.l1t[(size_t)(c0 + tr) * 512 + r0 + tc] = *(ushort2*)&o[0];
        *(ushort2*)&p.l1t[(size_t)(c0 + tr) * 512 + r0 + tc + 2] = *(ushort2*)&o[2];
    } else if (bid < 2464) {                // xm build: 1056 blocks, 8-elem groups
        int idx = (bid - 1408) * 256 + tid;
        int seg = idx & 63;
        int row = idx >> 6;
        int b = row / T_;
        int t = row - b * T_;
        const float* src;
        if (t < M_) src = p.meta + (size_t)t * 512 + seg * 8;
        else        src = p.x + ((size_t)b * S_ + (t - M_)) * 512 + seg * 8;
        float v[8];
        *(float4*)&v[0] = *(const float4*)src;
        *(float4*)&v[4] = *(const float4*)(src + 4);
        pack8(p.xm + (size_t)row * 512 + seg * 8, v);
    } else {                                // alr: 1056 blocks x 4 rows (f32 sources)
        int r = (bid - 2464) * 4 + (tid >> 6);
        int lane = tid & 63;
        int b = r / T_;
        int t = r - b * T_;
        const float* row = (t < M_) ? (p.meta + (size_t)t * 512)
                                    : (p.x + ((size_t)b * S_ + (t - M_)) * 512);
        float s = 0.f;
#pragma unroll
        for (int k = 0; k < 8; ++k) s = fmaf(row[lane + k * 64], p.wlr[lane + k * 64], s);
#pragma unroll
        for (int off = 32; off >= 1; off >>= 1) s += __shfl_xor(s, off, 64);
        if (lane == 0) p.alr[r] = 0.01f / (1.0f + expf(-s));
    }
}

// ---------------- bf16 MFMA GEMM (K=512) with fused epilogues, reg-prefetch pipeline ----------------
// MODE 0 QKV (N=1536: qq->U0, kk->U1 + kkT->U2, vv->U3)
// MODE 1 H1  (h1 bf->U0 + h1T->U2, dsilu(z0) bf->U3; residual kk=U1)
// MODE 2 Z1DP(dz1->U0 + dz1T->U2, dp bf->U4; reads h1b=U1, v=U3, alr)
// MODE 3 DH1DZ0 (dz0 T-major->U0; reads dp=U1, dsz0=U2)
// MODE 4 RES2 (U0 = bf(U1)+silu(acc))
// MODE 5 SWAQKV (N=1536: qh->U0, kh->U1, vhT per-batch transposed->U2)
// MODE 6 WO (row-filtered fp32 out->F0)
template<int MODE>
__global__ __launch_bounds__(256)
void mgemm(const ushort_t* __restrict__ A, const ushort_t* __restrict__ Bt,
           float* __restrict__ F0,
           ushort_t* __restrict__ U0, ushort_t* __restrict__ U1,
           ushort_t* __restrict__ U2, ushort_t* __restrict__ U3,
           ushort_t* __restrict__ U4,
           const float* __restrict__ alrp) {
    __shared__ ushort_t As[64 * 64];
    __shared__ ushort_t Bs[64 * 64];
    int tid = threadIdx.x;
    int m0 = blockIdx.x * 64, n0 = blockIdx.y * 64;
    int srow = tid >> 2;
    int sseg = (tid & 3) << 1;
    int wid = tid >> 6;
    int lane = tid & 63;
    int wm = (wid & 1) << 5;
    int wn = (wid >> 1) << 5;
    int fr = lane & 15;
    int fq = lane >> 4;
    int sw = srow & 7;
    const ushort_t* ga = A  + (size_t)(m0 + srow) * 512 + sseg * 8;
    const ushort_t* gb = Bt + (size_t)(n0 + srow) * 512 + sseg * 8;
    int4 av0 = *(const int4*)ga;
    int4 av1 = *(const int4*)(ga + 8);
    int4 bv0 = *(const int4*)gb;
    int4 bv1 = *(const int4*)(gb + 8);
    f32x4 acc[2][2] = {};
    for (int k0 = 0; k0 < 512; k0 += 64) {
        __syncthreads();
        *(int4*)&As[srow * 64 + ((sseg    ) ^ sw) * 8] = av0;
        *(int4*)&As[srow * 64 + ((sseg + 1) ^ sw) * 8] = av1;
        *(int4*)&Bs[srow * 64 + ((sseg    ) ^ sw) * 8] = bv0;
        *(int4*)&Bs[srow * 64 + ((sseg + 1) ^ sw) * 8] = bv1;
        __syncthreads();
        if (k0 + 64 < 512) {                 // prefetch overlaps MFMA phase
            av0 = *(const int4*)(ga + k0 + 64);
            av1 = *(const int4*)(ga + k0 + 72);
            bv0 = *(const int4*)(gb + k0 + 64);
            bv1 = *(const int4*)(gb + k0 + 72);
        }
#pragma unroll
        for (int ks = 0; ks < 2; ++ks) {
            int seg = fq + ks * 4;
            int rA0 = wm + fr,      rA1 = wm + 16 + fr;
            int rB0 = wn + fr,      rB1 = wn + 16 + fr;
            s16x8 a0 = *(const s16x8*)&As[rA0 * 64 + (seg ^ (rA0 & 7)) * 8];
            s16x8 a1 = *(const s16x8*)&As[rA1 * 64 + (seg ^ (rA1 & 7)) * 8];
            s16x8 b0 = *(const s16x8*)&Bs[rB0 * 64 + (seg ^ (rB0 & 7)) * 8];
            s16x8 b1 = *(const s16x8*)&Bs[rB1 * 64 + (seg ^ (rB1 & 7)) * 8];
            acc[0][0] = __builtin_amdgcn_mfma_f32_16x16x32_bf16(a0, b0, acc[0][0], 0, 0, 0);
            acc[0][1] = __builtin_amdgcn_mfma_f32_16x16x32_bf16(a0, b1, acc[0][1], 0, 0, 0);
            acc[1][0] = __builtin_amdgcn_mfma_f32_16x16x32_bf16(a1, b0, acc[1][0], 0, 0, 0);
            acc[1][1] = __builtin_amdgcn_mfma_f32_16x16x32_bf16(a1, b1, acc[1][1], 0, 0, 0);
        }
    }
#pragma unroll
    for (int i = 0; i < 2; ++i) {
        int row0 = m0 + wm + i * 16 + fq * 4;
        float c4[4];
        if (MODE == 2) {
#pragma unroll
            for (int r = 0; r < 4; ++r) c4[r] = (2.0f / 512.0f) * alrp[row0 + r];
        }
#pragma unroll
        for (int j = 0; j < 2; ++j) {
            int col = n0 + wn + j * 16 + fr;
            if (MODE == 0) {
                int sg = col >> 9, cl = col & 511;
                ushort_t t4[4];
#pragma unroll
                for (int r = 0; r < 4; ++r) t4[r] = f2bf(acc[i][j][r]);
                if (sg == 0) {
#pragma unroll
                    for (int r = 0; r < 4; ++r) U0[(size_t)(row0 + r) * 512 + cl] = t4[r];
                } else if (sg == 1) {
#pragma unroll
                    for (int r = 0; r < 4; ++r) U1[(size_t)(row0 + r) * 512 + cl] = t4[r];
                    *(uint2*)&U2[(size_t)cl * BT_ + row0] = *(uint2*)t4;   // kkT
                } else {
#pragma unroll
                    for (int r = 0; r < 4; ++r) U3[(size_t)(row0 + r) * 512 + cl] = t4[r];
                }
            } else if (MODE == 5) {
                int sg = col >> 9, cl = col & 511;
                ushort_t t4[4];
#pragma unroll
                for (int r = 0; r < 4; ++r) t4[r] = f2bf(acc[i][j][r]);
                if (sg == 0) {
#pragma unroll
                    for (int r = 0; r < 4; ++r) U0[(size_t)(row0 + r) * 512 + cl] = t4[r];
                } else if (sg == 1) {
#pragma unroll
                    for (int r = 0; r < 4; ++r) U1[(size_t)(row0 + r) * 512 + cl] = t4[r];
                } else {
                    int bb = row0 / T_;
                    int t0 = row0 - bb * T_;
                    *(uint2*)&U2[((size_t)(bb * 512) + cl) * T_ + t0] = *(uint2*)t4;  // vhT
                }
            } else if (MODE == 1) {
                ushort_t t4[4];
#pragma unroll
                for (int r = 0; r < 4; ++r) {
                    size_t off = (size_t)(row0 + r) * 512 + col;
                    float z = acc[i][j][r];
                    float h = bf2f(U1[off]) + siluf(z);
                    ushort_t hb = f2bf(h);
                    U0[off] = hb;
                    t4[r] = hb;
                    U3[off] = f2bf(dsiluf(z));                             // dsilu(z0)
                }
                *(uint2*)&U2[(size_t)col * BT_ + row0] = *(uint2*)t4;      // h1T
            } else if (MODE == 2) {
                ushort_t t4[4];
#pragma unroll
                for (int r = 0; r < 4; ++r) {
                    size_t off = (size_t)(row0 + r) * 512 + col;
                    float z = acc[i][j][r];
                    float s = 1.f / (1.f + expf(-z));
                    float d = c4[r] * (bf2f(U1[off]) + z * s - bf2f(U3[off]));
                    U4[off] = f2bf(d);                                     // dp
                    ushort_t u = f2bf(d * (s * (1.f + z * (1.f - s))));
                    U0[off] = u;
                    t4[r] = u;
                }
                *(uint2*)&U2[(size_t)col * BT_ + row0] = *(uint2*)t4;      // dz1T
            } else if (MODE == 3) {
                ushort_t t4[4];
#pragma unroll
                for (int r = 0; r < 4; ++r) {
                    size_t off = (size_t)(row0 + r) * 512 + col;
                    float g = bf2f(U1[off]) + acc[i][j][r];
                    t4[r] = f2bf(g * bf2f(U2[off]));
                }
                *(uint2*)&U0[(size_t)col * BT_ + row0] = *(uint2*)t4;      // dz0T
            } else if (MODE == 4) {
#pragma unroll
                for (int r = 0; r < 4; ++r) {
                    size_t off = (size_t)(row0 + r) * 512 + col;
                    U0[off] = f2bf(bf2f(U1[off]) + siluf(acc[i][j][r]));
                }
            } else if (MODE == 6) {
#pragma unroll
                for (int r = 0; r < 4; ++r) {
                    int row = row0 + r;
                    int bb = row / T_;
                    int t = row - bb * T_;
                    if (t >= M_) F0[((size_t)bb * S_ + (t - M_)) * 512 + col] = acc[i][j][r];
                }
            }
        }
    }
}

// ---------------- combined dW NT GEMM (both layers): z in [0,12), layer = z/6 ----------------
__global__ __launch_bounds__(256)
void gemm_dw2(const ushort_t* __restrict__ A1T, const ushort_t* __restrict__ B1T,
              const ushort_t* __restrict__ A0T, const ushort_t* __restrict__ B0T,
              float* __restrict__ Cpart) {
    __shared__ ushort_t As[64 * 64];
    __shared__ ushort_t Bs[64 * 64];
    int tid = threadIdx.x;
    int zz = blockIdx.z;
    int layer = (zz >= 6);
    int slice = layer ? (zz - 6) : zz;
    const ushort_t* AT  = layer ? A1T : A0T;
    const ushort_t* BT2 = layer ? B1T : B0T;
    int m0 = blockIdx.x * 64, n0 = blockIdx.y * 64;
    int kbase = slice * 704;
    int srow = tid >> 2;
    int sseg = (tid & 3) << 1;
    int wid = tid >> 6;
    int lane = tid & 63;
    int wm = (wid & 1) << 5;
    int wn = (wid >> 1) << 5;
    int fr = lane & 15;
    int fq = lane >> 4;
    int sw = srow & 7;
    const ushort_t* ga = AT  + (size_t)(m0 + srow) * BT_ + kbase + sseg * 8;
    const ushort_t* gb = BT2 + (size_t)(n0 + srow) * BT_ + kbase + sseg * 8;
    int4 av0 = *(const int4*)ga;
    int4 av1 = *(const int4*)(ga + 8);
    int4 bv0 = *(const int4*)gb;
    int4 bv1 = *(const int4*)(gb + 8);
    f32x4 acc[2][2] = {};
    for (int kt = 0; kt < 11; ++kt) {
        __syncthreads();
        *(int4*)&As[srow * 64 + ((sseg    ) ^ sw) * 8] = av0;
        *(int4*)&As[srow * 64 + ((sseg + 1) ^ sw) * 8] = av1;
        *(int4*)&Bs[srow * 64 + ((sseg    ) ^ sw) * 8] = bv0;
        *(int4*)&Bs[srow * 64 + ((sseg + 1) ^ sw) * 8] = bv1;
        __syncthreads();
        if (kt < 10) {
            int koff = (kt + 1) * 64;
            av0 = *(const int4*)(ga + koff);
            av1 = *(const int4*)(ga + koff + 8);
            bv0 = *(const int4*)(gb + koff);
            bv1 = *(const int4*)(gb + koff + 8);
        }
#pragma unroll
        for (int ks = 0; ks < 2; ++ks) {
            int seg = fq + ks * 4;
            int rA0 = wm + fr,      rA1 = wm + 16 + fr;
            int rB0 = wn + fr,      rB1 = wn + 16 + fr;
            s16x8 a0 = *(const s16x8*)&As[rA0 * 64 + (seg ^ (rA0 & 7)) * 8];
            s16x8 a1 = *(const s16x8*)&As[rA1 * 64 + (seg ^ (rA1 & 7)) * 8];
            s16x8 b0 = *(const s16x8*)&Bs[rB0 * 64 + (seg ^ (rB0 & 7)) * 8];
            s16x8 b1 = *(const s16x8*)&Bs[rB1 * 64 + (seg ^ (rB1 & 7)) * 8];
            acc[0][0] = __builtin_amdgcn_mfma_f32_16x16x32_bf16(a0, b0, acc[0][0], 0, 0, 0);
            acc[0][1] = __builtin_amdgcn_mfma_f32_16x16x32_bf16(a0, b1, acc[0][1], 0, 0, 0);
            acc[1][0] = __builtin_amdgcn_mfma_f32_16x16x32_bf16(a1, b0, acc[1][0], 0, 0, 0);
            acc[1][1] = __builtin_amdgcn_mfma_f32_16x16x32_bf16(a1, b1, acc[1][1], 0, 0, 0);
        }
    }
    float* C = Cpart + (size_t)zz * 262144;
#pragma unroll
    for (int i = 0; i < 2; ++i)
#pragma unroll
        for (int j = 0; j < 2; ++j)
#pragma unroll
            for (int r = 0; r < 4; ++r)
                C[(size_t)(m0 + wm + i * 16 + fq * 4 + r) * 512 + n0 + wn + j * 16 + fr] =
                    acc[i][j][r];
}

// ---------------- AdamW first step (6 partial slices per layer) -> bf16 weights ----------------
__global__ void adam_kernel(const float* __restrict__ W, const float* __restrict__ dWp,
                            ushort_t* __restrict__ Wnb) {
    int idx = blockIdx.x * 256 + threadIdx.x;
    int layer = idx >> 18;
    int i = idx & 262143;
    const float* base = dWp + (size_t)layer * 6 * 262144 + i;
    float g = 0.f;
#pragma unroll
    for (int z = 0; z < 6; ++z) g += base[(size_t)z * 262144];
    g *= (1.0f / 16.0f);
    float w = W[idx];
    float o = w * (1.0f - 1e-5f) - 1e-3f * g / (fabsf(g) + 1e-8f);
    Wnb[idx] = f2bf(o);
}

// ---------------- MFMA flash SWA, unnormalized softmax (scores bounded) ----------------
__global__ __launch_bounds__(256)
void swa_mfma(const ushort_t* __restrict__ qh, const ushort_t* __restrict__ kh,
              const ushort_t* __restrict__ vhT, ushort_t* __restrict__ ao) {
    __shared__ ushort_t Qs[64 * 64];
    __shared__ ushort_t Ks[64 * 64];
    __shared__ ushort_t Vs[64 * 64];
    __shared__ ushort_t Pw[4][16 * 72];
    int qt = 32 - (int)blockIdx.x;
    int hh = blockIdx.y;
    int b  = blockIdx.z;
    int tid = threadIdx.x;
    int wave = tid >> 6, lane = tid & 63;
    int fr = lane & 15, fq = lane >> 4;
    int tok = tid & 63, cs0 = tid >> 6;

    {
        const ushort_t* src = qh + ((size_t)(b * T_ + qt * 64 + tok)) * 512 + hh * 64;
#pragma unroll
        for (int p = 0; p < 2; ++p) {
            int seg = cs0 + p * 4;
            *(int4*)&Qs[tok * 64 + ((seg ^ (tok & 7)) << 3)] = *(const int4*)(src + seg * 8);
        }
    }
    __syncthreads();
    s16x8 qf0 = *(const s16x8*)&Qs[(wave * 16 + fr) * 64 + (((0 + fq) ^ (fr & 7)) << 3)];
    s16x8 qf1 = *(const s16x8*)&Qs[(wave * 16 + fr) * 64 + (((4 + fq) ^ (fr & 7)) << 3)];

    int i_q = qt * 64 + wave * 16 + fr;
    int iqmin = qt * 64 + wave * 16;
    float l_i = 0.f;
    f32x4 o[4] = {};
    int jstart = qt * 64 - (WIN_ - 1);
    if (jstart < 0) jstart = 0;
    jstart &= ~63;
    int jend = qt * 64;
    const ushort_t* kp = kh + ((size_t)(b * T_ + jstart + tok)) * 512 + hh * 64;
    const ushort_t* vp = vhT + ((size_t)(b * 512 + hh * 64 + tok)) * T_ + jstart;
    int4 ka = *(const int4*)(kp + cs0 * 8);
    int4 kb2 = *(const int4*)(kp + (cs0 + 4) * 8);
    int4 va = *(const int4*)(vp + cs0 * 8);
    int4 vb2 = *(const int4*)(vp + (cs0 + 4) * 8);
    for (int jb = jstart; jb <= jend; jb += 64) {
        __syncthreads();
        *(int4*)&Ks[tok * 64 + (((cs0    ) ^ (tok & 7)) << 3)] = ka;
        *(int4*)&Ks[tok * 64 + (((cs0 + 4) ^ (tok & 7)) << 3)] = kb2;
        *(int4*)&Vs[tok * 64 + (((cs0    ) ^ (tok & 7)) << 3)] = va;
        *(int4*)&Vs[tok * 64 + (((cs0 + 4) ^ (tok & 7)) << 3)] = vb2;
        __syncthreads();
        if (jb + 64 <= jend) {
            kp += 64 * 512;
            vp += 64;
            ka  = *(const int4*)(kp + cs0 * 8);
            kb2 = *(const int4*)(kp + (cs0 + 4) * 8);
            va  = *(const int4*)(vp + cs0 * 8);
            vb2 = *(const int4*)(vp + (cs0 + 4) * 8);
        }
        f32x4 sa[4] = {};
#pragma unroll
        for (int kf = 0; kf < 4; ++kf) {
            int krow = kf * 16 + fr;
            s16x8 a0 = *(const s16x8*)&Ks[krow * 64 + (((0 + fq) ^ (fr & 7)) << 3)];
            s16x8 a1 = *(const s16x8*)&Ks[krow * 64 + (((4 + fq) ^ (fr & 7)) << 3)];
            sa[kf] = __builtin_amdgcn_mfma_f32_16x16x32_bf16(a0, qf0, sa[kf], 0, 0, 0);
            sa[kf] = __builtin_amdgcn_mfma_f32_16x16x32_bf16(a1, qf1, sa[kf], 0, 0, 0);
        }
        float psum = 0.f;
        bool full = (jb + 63 <= iqmin) && (jb >= iqmin + 15 - (WIN_ - 1));
        if (full) {
#pragma unroll
            for (int kf = 0; kf < 4; ++kf)
#pragma unroll
                for (int r = 0; r < 4; ++r) {
                    float p = __expf(sa[kf][r] * 0.125f);
                    ushort_t pb = f2bf(p);
                    psum += bf2f(pb);
                    Pw[wave][fr * 72 + kf * 16 + fq * 4 + r] = pb;
                }
        } else {
#pragma unroll
            for (int kf = 0; kf < 4; ++kf)
#pragma unroll
                for (int r = 0; r < 4; ++r) {
                    int j2 = jb + kf * 16 + fq * 4 + r;
                    bool valid = (j2 <= i_q) && (i_q - j2 < WIN_);
                    float p = valid ? __expf(sa[kf][r] * 0.125f) : 0.f;
                    ushort_t pb = f2bf(p);
                    psum += bf2f(pb);
                    Pw[wave][fr * 72 + kf * 16 + fq * 4 + r] = pb;
                }
        }
        psum += __shfl_xor(psum, 16);
        psum += __shfl_xor(psum, 32);
        l_i += psum;
#pragma unroll
        for (int ks = 0; ks < 2; ++ks) {
            s16x8 pa = *(const s16x8*)&Pw[wave][fr * 72 + ks * 32 + fq * 8];
#pragma unroll
            for (int nf = 0; nf < 4; ++nf) {
                int vrow = nf * 16 + fr;
                s16x8 bv = *(const s16x8*)&Vs[vrow * 64 + (((ks * 4 + fq) ^ (fr & 7)) << 3)];
                o[nf] = __builtin_amdgcn_mfma_f32_16x16x32_bf16(pa, bv, o[nf], 0, 0, 0);
            }
        }
    }
    float linv = 1.0f / l_i;
    float l0 = __shfl(linv, fq * 4 + 0);
    float l1 = __shfl(linv, fq * 4 + 1);
    float l2 = __shfl(linv, fq * 4 + 2);
    float l3 = __shfl(linv, fq * 4 + 3);
#pragma unroll
    for (int nf = 0; nf < 4; ++nf) {
        int col = hh * 64 + nf * 16 + fr;
        size_t row0 = (size_t)(b * T_) + qt * 64 + wave * 16 + fq * 4;
        ao[(row0 + 0) * 512 + col] = f2bf(o[nf][0] * l0);
        ao[(row0 + 1) * 512 + col] = f2bf(o[nf][1] * l1);
        ao[(row0 + 2) * 512 + col] = f2bf(o[nf][2] * l2);
        ao[(row0 + 3) * 512 + col] = f2bf(o[nf][3] * l3);
    }
}

extern "C" void kernel_launch(void* const* d_in, const int* in_sizes, int n_in,
                              void* d_out, int out_size, void* d_ws, size_t ws_size,
                              hipStream_t stream) {
    (void)in_sizes; (void)n_in; (void)out_size; (void)ws_size;
    const float* x      = (const float*)d_in[0];
    const float* meta   = (const float*)d_in[1];
    const float* lmm_w  = (const float*)d_in[2];
    const float* w_q    = (const float*)d_in[3];
    const float* w_k    = (const float*)d_in[4];
    const float* w_v    = (const float*)d_in[5];
    const float* w_lr   = (const float*)d_in[6];
    const float* swa_wq = (const float*)d_in[7];
    const float* swa_wk = (const float*)d_in[8];
    const float* swa_wv = (const float*)d_in[9];
    const float* swa_wo = (const float*)d_in[10];
    float* out = (float*)d_out;
    float* ws  = (float*)d_ws;

    const size_t BTD = (size_t)BT_ * D_;       // 2162688
    float* alr = ws;                           // BT_
    float* dWp = alr + BT_;                    // [2][6][262144] fp32
    ushort_t* xb = (ushort_t*)(dWp + 12 * 262144);
    ushort_t* B0  = xb + 0 * BTD;   // xm / dz0T / h1q
    ushort_t* B1  = xb + 1 * BTD;   // qq / qh
    ushort_t* B2  = xb + 2 * BTD;   // kk / ao
    ushort_t* B3  = xb + 3 * BTD;   // kkT
    ushort_t* B4  = xb + 4 * BTD;   // vv / r
    ushort_t* B5  = xb + 5 * BTD;   // h1b / kh
    ushort_t* B6  = xb + 6 * BTD;   // h1T / vhT
    ushort_t* B7  = xb + 7 * BTD;   // dz1
    ushort_t* B8  = xb + 8 * BTD;   // dz1T
    ushort_t* B9  = xb + 9 * BTD;   // dp bf
    ushort_t* B10 = xb + 10 * BTD;  // dsilu(z0) bf
    ushort_t* wbf = xb + 11 * BTD;
    ushort_t* wq_bf  = wbf + 0 * 262144;       // wq,wk,wv contiguous
    ushort_t* l0_bf  = wbf + 3 * 262144;
    ushort_t* l1_bf  = wbf + 4 * 262144;
    ushort_t* sq_bf  = wbf + 5 * 262144;       // sq,sk,sv contiguous
    ushort_t* wo_bf  = wbf + 8 * 262144;
    ushort_t* l1t_bf = wbf + 9 * 262144;
    ushort_t* wn_bf  = wbf + 10 * 262144;      // 2 layers

    dim3 blk(256);
    dim3 gg(66, 8);
    dim3 gq(66, 24);
    dim3 gdw(8, 8, 12);

    PrepArgs pa;
    pa.wsrc[0] = w_q;    pa.wdst[0] = wq_bf;
    pa.wsrc[1] = w_k;    pa.wdst[1] = wbf + 1 * 262144;
    pa.wsrc[2] = w_v;    pa.wdst[2] = wbf + 2 * 262144;
    pa.wsrc[3] = lmm_w;  pa.wdst[3] = l0_bf;
    pa.wsrc[4] = lmm_w + 262144; pa.wdst[4] = l1_bf;
    pa.wsrc[5] = swa_wq; pa.wdst[5] = sq_bf;
    pa.wsrc[6] = swa_wk; pa.wdst[6] = wbf + 6 * 262144;
    pa.wsrc[7] = swa_wv; pa.wdst[7] = wbf + 7 * 262144;
    pa.wsrc[8] = swa_wo; pa.wdst[8] = wo_bf;
    pa.l1src = lmm_w + 262144; pa.l1t = l1t_bf;
    pa.x = x; pa.meta = meta; pa.xm = B0;
    pa.wlr = w_lr; pa.alr = alr;

    prep_kernel<<<dim3(3520), blk, 0, stream>>>(pa);
    // qq(B1)/kk(B2)+kkT(B3)/vv(B4) = xm @ {wq,wk,wv}^T
    mgemm<0><<<gq, blk, 0, stream>>>(B0, wq_bf, nullptr, B1, B2, B3, B4, nullptr, nullptr);
    // h1b(B5)+h1T(B6), dsz0(B10); residual kk(B2)
    mgemm<1><<<gg, blk, 0, stream>>>(B2, l0_bf, nullptr, B5, B2, B6, B10, nullptr, nullptr);
    // dz1(B7)+dz1T(B8), dp(B9); reads h1b(B5), v(B4), alr
    mgemm<2><<<gg, blk, 0, stream>>>(B5, l1_bf, nullptr, B7, B5, B8, B4, B9, alr);
    // dz0T(B0); reads dp(B9), dsz0(B10)
    mgemm<3><<<gg, blk, 0, stream>>>(B7, l1t_bf, nullptr, B0, B9, B10, nullptr, nullptr, nullptr);
    // dW1 = dz1T x h1T (z 6..11), dW0 = dz0T x kkT (z 0..5)
    gemm_dw2<<<gdw, blk, 0, stream>>>(B8, B6, B0, B3, dWp);
    adam_kernel<<<dim3(2048), blk, 0, stream>>>(lmm_w, dWp, wn_bf);
    // h1q(B0) = qq + silu(qq@Wn0^T)
    mgemm<4><<<gg, blk, 0, stream>>>(B1, wn_bf, nullptr, B0, B1, nullptr, nullptr, nullptr, nullptr);
    // r(B4) = h1q + silu(h1q@Wn1^T)
    mgemm<4><<<gg, blk, 0, stream>>>(B0, wn_bf + 262144, nullptr, B4, B0, nullptr, nullptr, nullptr, nullptr);
    // qh(B1)/kh(B5)/vhT(B6) = r @ {sq,sk,sv}^T
    mgemm<5><<<gq, blk, 0, stream>>>(B4, sq_bf, nullptr, B1, B5, B6, nullptr, nullptr, nullptr);
    swa_mfma<<<dim3(33, 8, 2), blk, 0, stream>>>(B1, B5, B6, B2); // ao(B2)
    // out = ao @ wo^T (row-filtered fp32)
    mgemm<6><<<gg, blk, 0, stream>>>(B2, wo_bf, out, nullptr, nullptr, nullptr, nullptr, nullptr, nullptr);
}